// Round 4
// baseline (580.725 us; speedup 1.0000x reference)
//
#include <hip/hip_runtime.h>

typedef short short8 __attribute__((ext_vector_type(8)));
typedef float floatx4 __attribute__((ext_vector_type(4)));

#define LEAKY(v) ((v) >= 0.0f ? (v) : 0.01f * (v))

constexpr int D = 256;  // in = hid = out = 256

__device__ __forceinline__ short f2bf(float x) {
  unsigned u = __float_as_uint(x);
  u += 0x7fffu + ((u >> 16) & 1u);  // RNE (finite inputs)
  return (short)(u >> 16);
}
__device__ __forceinline__ float bf2f(short s) {
  return __uint_as_float(((unsigned)(unsigned short)s) << 16);
}

// ---- W transpose+convert: Wt[n][k] = bf16(Wsrc[k][n]), 3 matrices ----------
__global__ void transpose_w(const float* __restrict__ W1,
                            const float* __restrict__ W2,
                            const float* __restrict__ Wl,
                            short* __restrict__ Wt) {
  __shared__ float t[32][33];
  const float* src = (blockIdx.z == 0) ? W1 : (blockIdx.z == 1) ? W2 : Wl;
  short* dst = Wt + (size_t)blockIdx.z * D * D;
  int tx = threadIdx.x, ty = threadIdx.y;
  t[ty][tx] = src[(size_t)(blockIdx.y * 32 + ty) * D + blockIdx.x * 32 + tx];
  __syncthreads();
  dst[(size_t)(blockIdx.x * 32 + ty) * D + blockIdx.y * 32 + tx] =
      f2bf(t[tx][ty]);
}

// ---- MFMA GEMM, no LDS: C[M,256] = A[M,256] @ Wt^T (+epilogue) -------------
// 256 threads = 4 waves; wave w covers cols w*64..w*64+63 (4 n-frags);
// 4 m-frags of 16 rows each -> block covers 64 rows x 256 cols.
// A-frag: lane l holds A[rowBase+i*16+(l&15)][k0 + (l>>4)*8 .. +7] (16B).
// B-frag: lane l holds Wt[w*64+j*16+(l&15)][k0 + (l>>4)*8 .. +7]   (16B).
// W is 128KB -> L2-resident; A rows hit L1 (4 waves share tile). No barriers.
template <bool A_F32, bool ADD_ROW, bool FINAL>
__global__ __launch_bounds__(256) void gemm_mfma(
    const void* __restrict__ Avoid, const short* __restrict__ Wt,
    const float* __restrict__ R, const int* __restrict__ batch,
    const float* __restrict__ bias, void* __restrict__ Cvoid, int M) {
  const int tid = threadIdx.x;
  const int l = tid & 63, w = tid >> 6, lm = l & 15, q = l >> 4;
  const int rowBase = blockIdx.x * 64;

  floatx4 acc[4][4];
#pragma unroll
  for (int i = 0; i < 4; i++)
#pragma unroll
    for (int j = 0; j < 4; j++) acc[i][j] = (floatx4){0.f, 0.f, 0.f, 0.f};

  // clamped per-lane A rows (invalid rows computed but never stored)
  int arow[4];
#pragma unroll
  for (int i = 0; i < 4; i++) {
    int r0 = rowBase + i * 16 + lm;
    arow[i] = (r0 < M) ? r0 : (M - 1);
  }
  const short* bbase = Wt + (size_t)(w * 64 + lm) * D + q * 8;

#pragma unroll
  for (int k0 = 0; k0 < D; k0 += 32) {
    short8 a[4], b[4];
    if (A_F32) {
      const float* Af = (const float*)Avoid;
#pragma unroll
      for (int i = 0; i < 4; i++) {
        const float* ap = Af + (size_t)arow[i] * D + k0 + q * 8;
        float4 v0 = ((const float4*)ap)[0];
        float4 v1 = ((const float4*)ap)[1];
        short8 s;
        s[0] = f2bf(v0.x); s[1] = f2bf(v0.y); s[2] = f2bf(v0.z); s[3] = f2bf(v0.w);
        s[4] = f2bf(v1.x); s[5] = f2bf(v1.y); s[6] = f2bf(v1.z); s[7] = f2bf(v1.w);
        a[i] = s;
      }
    } else {
      const short* Ab = (const short*)Avoid;
#pragma unroll
      for (int i = 0; i < 4; i++)
        a[i] = *(const short8*)(Ab + (size_t)arow[i] * D + k0 + q * 8);
    }
#pragma unroll
    for (int j = 0; j < 4; j++)
      b[j] = *(const short8*)(bbase + (size_t)j * 16 * D + k0);
#pragma unroll
    for (int i = 0; i < 4; i++)
#pragma unroll
      for (int j = 0; j < 4; j++)
        acc[i][j] = __builtin_amdgcn_mfma_f32_16x16x32_bf16(a[i], b[j],
                                                            acc[i][j], 0, 0, 0);
  }

  // ---- epilogue: D reg r -> row = i*16 + q*4 + r, col = w*64 + j*16 + lm ----
#pragma unroll
  for (int i = 0; i < 4; i++) {
#pragma unroll
    for (int r = 0; r < 4; r++) {
      int row = rowBase + i * 16 + q * 4 + r;
      if (row < M) {
        int rb = 0;
        if (ADD_ROW) rb = batch[row];
        if (!FINAL) {
          short* C = (short*)Cvoid;
#pragma unroll
          for (int j = 0; j < 4; j++) {
            int col = w * 64 + j * 16 + lm;
            float c = acc[i][j][r];
            if (ADD_ROW) c += R[(size_t)rb * D + col];
            C[(size_t)row * D + col] = f2bf(c);
          }
        } else {
          float* C = (float*)Cvoid;
#pragma unroll
          for (int j = 0; j < 4; j++) {
            int col = w * 64 + j * 16 + lm;
            float c = acc[i][j][r];
            if (ADD_ROW) c += R[(size_t)rb * D + col];
            c += bias[col];
            c = LEAKY(c);
            C[(size_t)row * D + col] = c;
          }
        }
      }
    }
  }
}

// ---------------- CSR build --------------------------------------------------
__global__ void count_dst(const int* __restrict__ dst, int* __restrict__ offs,
                          int E) {
  int e = blockIdx.x * 256 + threadIdx.x;
  if (e < E) atomicAdd(&offs[dst[e]], 1);
}

__global__ void scan_blocks(int* __restrict__ offs, int* __restrict__ bsums,
                            int n) {
  __shared__ int tmp[256];
  int i = blockIdx.x * 256 + threadIdx.x;
  int v = (i < n) ? offs[i] : 0;
  tmp[threadIdx.x] = v;
  __syncthreads();
  for (int off = 1; off < 256; off <<= 1) {
    int t = (threadIdx.x >= off) ? tmp[threadIdx.x - off] : 0;
    __syncthreads();
    tmp[threadIdx.x] += t;
    __syncthreads();
  }
  if (i < n) offs[i] = tmp[threadIdx.x] - v;
  if (threadIdx.x == 255) bsums[blockIdx.x] = tmp[255];
}

__global__ void scan_sums(int* __restrict__ bs, int nb) {
  __shared__ int tmp[1024];
  int v = (threadIdx.x < nb) ? bs[threadIdx.x] : 0;
  tmp[threadIdx.x] = v;
  __syncthreads();
  for (int off = 1; off < 1024; off <<= 1) {
    int t = (threadIdx.x >= off) ? tmp[threadIdx.x - off] : 0;
    __syncthreads();
    tmp[threadIdx.x] += t;
    __syncthreads();
  }
  if (threadIdx.x < nb) bs[threadIdx.x] = tmp[threadIdx.x] - v;
}

__global__ void add_offsets(int* __restrict__ offs, const int* __restrict__ bs,
                            int n, int* __restrict__ cursor) {
  int i = blockIdx.x * 256 + threadIdx.x;
  if (i < n) {
    int o = offs[i] + bs[blockIdx.x];
    offs[i] = o;
    cursor[i] = o;
  }
}

__global__ void fill_buckets(const int* __restrict__ src,
                             const int* __restrict__ dst,
                             const float* __restrict__ vals,
                             int* __restrict__ cursor, int* __restrict__ esrc,
                             float* __restrict__ ew, int E) {
  int e = blockIdx.x * 256 + threadIdx.x;
  if (e < E) {
    int p = atomicAdd(&cursor[dst[e]], 1);
    esrc[p] = src[e];
    ew[p] = vals[e];
  }
}

// ---- gather agg (bf16 in/out): out[n] = bf16(leaky(sum w*H[src] + bias)) ---
__global__ __launch_bounds__(256) void aggregate_bf(
    const short* __restrict__ H, const int* __restrict__ offs,
    const int* __restrict__ esrc, const float* __restrict__ ew,
    const float* __restrict__ bias, short* __restrict__ out, int N, int E) {
  int node = blockIdx.x * 4 + (threadIdx.x >> 6);
  if (node >= N) return;
  int lane = threadIdx.x & 63;
  int beg = offs[node];
  int end = (node == N - 1) ? E : offs[node + 1];
  float a0 = 0.f, a1 = 0.f, a2 = 0.f, a3 = 0.f;
  for (int i = beg; i < end; i++) {
    int s = esrc[i];
    float wv = ew[i];
    uint2 pk = ((const uint2*)(H + (size_t)s * D))[lane];
    a0 += wv * bf2f((short)(pk.x & 0xffff));
    a1 += wv * bf2f((short)(pk.x >> 16));
    a2 += wv * bf2f((short)(pk.y & 0xffff));
    a3 += wv * bf2f((short)(pk.y >> 16));
  }
  float4 b = ((const float4*)bias)[lane];
  a0 = LEAKY(a0 + b.x);
  a1 = LEAKY(a1 + b.y);
  a2 = LEAKY(a2 + b.z);
  a3 = LEAKY(a3 + b.w);
  uint2 o;
  o.x = (unsigned)(unsigned short)f2bf(a0) |
        ((unsigned)(unsigned short)f2bf(a1) << 16);
  o.y = (unsigned)(unsigned short)f2bf(a2) |
        ((unsigned)(unsigned short)f2bf(a3) << 16);
  ((uint2*)(out + (size_t)node * D))[lane] = o;
}

// ---- R1[b,:] = leaky(features[root_b]) @ W2[256:512] (fp32) ----------------
__global__ void root_gemm1(const float* __restrict__ X,
                           const int* __restrict__ root_idx,
                           const float* __restrict__ W2,
                           float* __restrict__ R1) {
  __shared__ float a[D];
  int b = blockIdx.x, j = threadIdx.x;
  int r = root_idx[b];
  a[j] = LEAKY(X[(size_t)r * D + j]);
  __syncthreads();
  float acc = 0.f;
#pragma unroll 8
  for (int k = 0; k < D; k++) acc += a[k] * W2[(size_t)(D + k) * D + j];
  R1[b * D + j] = acc;
}

// ---- R2[b,:] = (agg1[root_b]+b1) @ Wl[256:512]  (recompute agg for root) ---
__global__ void root_gemm2(const short* __restrict__ H,
                           const int* __restrict__ root_idx,
                           const int* __restrict__ offs,
                           const int* __restrict__ esrc,
                           const float* __restrict__ ew,
                           const float* __restrict__ b1,
                           const float* __restrict__ Wl, float* __restrict__ R2,
                           int N, int E) {
  __shared__ float a[D];
  int b = blockIdx.x, j = threadIdx.x;
  int r = root_idx[b];
  int beg = offs[r], end = (r == N - 1) ? E : offs[r + 1];
  float acc = b1[j];
  for (int e = beg; e < end; e++)
    acc += ew[e] * bf2f(H[(size_t)esrc[e] * D + j]);
  a[j] = acc;
  __syncthreads();
  float s = 0.f;
#pragma unroll 8
  for (int k = 0; k < D; k++) s += a[k] * Wl[(size_t)(D + k) * D + j];
  R2[b * D + j] = s;
}

extern "C" void kernel_launch(void* const* d_in, const int* in_sizes, int n_in,
                              void* d_out, int out_size, void* d_ws,
                              size_t ws_size, hipStream_t stream) {
  const float* features = (const float*)d_in[0];  // [N,256]
  const float* values   = (const float*)d_in[1];  // [E]
  const float* W1 = (const float*)d_in[2];        // [256,256]
  const float* b1 = (const float*)d_in[3];        // [256]
  const float* W2 = (const float*)d_in[4];        // [512,256]
  const float* b2 = (const float*)d_in[5];        // [256]
  const float* Wl = (const float*)d_in[6];        // [512,256]
  const float* bl = (const float*)d_in[7];        // [256]
  const int* adjs = (const int*)d_in[8];          // [2,E]
  const int* batch = (const int*)d_in[9];         // [N]
  const int* root_idx = (const int*)d_in[10];     // [B]

  const int N = in_sizes[0] / D;
  const int E = in_sizes[1];
  const int B = in_sizes[10];
  const int* srcI = adjs;
  const int* dstI = adjs + E;

  // workspace layout
  short* bf0 = (short*)d_ws;            // h0_bf, then h2_bf   [N*256]
  short* bf1 = bf0 + (size_t)N * D;     // a1_bf, then a2_bf   [N*256]
  short* Wt = bf1 + (size_t)N * D;      // 3 x [256,256] bf16 (n-major)
  float* R1 = (float*)(Wt + (size_t)3 * D * D);  // [B,256]
  float* R2 = R1 + (size_t)B * D;                // [B,256]
  float* ew = R2 + (size_t)B * D;                // [E]
  int* offs = (int*)(ew + E);                    // [N]
  int* cursor = offs + N;                        // [N]
  int* esrc = cursor + N;                        // [E]
  int* bsums = esrc + E;                         // [<=1024]

  const int nb = (N + 255) / 256;  // 391 <= 1024

  // ---- build dst-CSR (reused by both aggregations + root2) ----
  hipMemsetAsync(offs, 0, (size_t)N * sizeof(int), stream);
  count_dst<<<(E + 255) / 256, 256, 0, stream>>>(dstI, offs, E);
  scan_blocks<<<nb, 256, 0, stream>>>(offs, bsums, N);
  scan_sums<<<1, 1024, 0, stream>>>(bsums, nb);
  add_offsets<<<nb, 256, 0, stream>>>(offs, bsums, N, cursor);
  fill_buckets<<<(E + 255) / 256, 256, 0, stream>>>(srcI, dstI, values, cursor,
                                                    esrc, ew, E);

  // ---- weights -> bf16, transposed to [n][k] ----
  transpose_w<<<dim3(8, 8, 3), dim3(32, 32), 0, stream>>>(W1, W2, Wl, Wt);

  const int ggrid = (N + 63) / 64;
  const int aggGrid = (N + 3) / 4;

  // 1) h0 = features @ W1           (fp32 in, bf16 out)
  gemm_mfma<true, false, false><<<ggrid, 256, 0, stream>>>(
      features, Wt, nullptr, nullptr, nullptr, bf0, N);

  // 2) a1 = leaky(segsum(w*h0) + b1)  (bf16)
  aggregate_bf<<<aggGrid, 256, 0, stream>>>(bf0, offs, esrc, ew, b1, bf1, N, E);

  // 3) R1, R2 (root2 recomputes pre-leaky agg1 rows from CSR)
  root_gemm1<<<B, 256, 0, stream>>>(features, root_idx, W2, R1);
  root_gemm2<<<B, 256, 0, stream>>>(bf0, root_idx, offs, esrc, ew, b1, Wl, R2,
                                    N, E);

  // 4) h2 = a1 @ W2_top + R1[batch]   (bf16 in/out; overwrites h0 after root2)
  gemm_mfma<false, true, false><<<ggrid, 256, 0, stream>>>(
      bf1, Wt + (size_t)D * D, R1, batch, nullptr, bf0, N);

  // 5) a2 = leaky(segsum(w*h2) + b2)  (bf16)
  aggregate_bf<<<aggGrid, 256, 0, stream>>>(bf0, offs, esrc, ew, b2, bf1, N, E);

  // 6) out = leaky(a2 @ Wl_top + R2[batch] + bl)  (fp32 out)
  gemm_mfma<false, true, true><<<ggrid, 256, 0, stream>>>(
      bf1, Wt + (size_t)2 * D * D, R2, batch, bl, (float*)d_out, N);
}